// Round 5
// baseline (163.809 us; speedup 1.0000x reference)
//
#include <hip/hip_runtime.h>
#include <math.h>

#define G 4
#define NN 1024
#define FF 256
#define HH 256
#define BB 32
#define LL 4

typedef __attribute__((ext_vector_type(8))) short short8;
typedef __attribute__((ext_vector_type(8))) unsigned short ushort8;
typedef __attribute__((ext_vector_type(4))) unsigned short ushort4v;
typedef __attribute__((ext_vector_type(4))) float floatx4;

__device__ inline unsigned short f2bf(float f) {
  union { float f; unsigned u; } x; x.f = f;
  unsigned r = x.u + 0x7fffu + ((x.u >> 16) & 1u);  // RNE
  return (unsigned short)(r >> 16);
}
__device__ inline float bf2f(unsigned short u) {
  union { unsigned u; float f; } x; x.u = (unsigned)u << 16;
  return x.f;
}

// ---------------------------------------------------------------------------
// in64_tile: one block owns a 64-row x 256-col slab of graph g.
//   phase 1: x0 = relu(X @ w_in + b_in)  -> h0bf (global) + Xs (LDS)
//   phase 2: y0 = x0 @ W0                -> yT (transposed, bf16)
// K=256 is fully block-local, so no grid-wide dep; replaces the old
// separate g1(y0) dispatch and its xbf re-read.
// 4 waves; wave w owns rows [w*16, w*16+16), 16 n-frags each (acc[16]).
// ---------------------------------------------------------------------------
__device__ void in64_tile(int job, const float* __restrict__ X,
                          const float* __restrict__ w_in,
                          const float* __restrict__ b_in,
                          const float* __restrict__ gcn_w0,
                          unsigned short* __restrict__ h0bf,
                          unsigned short* __restrict__ yT, unsigned short* As,
                          unsigned short* Bs, unsigned short* Xs, int t) {
  const int mt = job & 15, g = job >> 4;
  const int m0 = mt * 64;
  const int lane = t & 63, w = t >> 6;
  const int l16 = lane & 15, quad = lane >> 4;

  floatx4 acc[16];
#pragma unroll
  for (int j = 0; j < 16; ++j) acc[j] = (floatx4){0.f, 0.f, 0.f, 0.f};

  for (int tt = 0; tt < 4; ++tt) {
    const int kb = tt * 64;
    __syncthreads();
    // A: X fp32 [64 rows][64 k] -> As bf16 (verified in_tile pattern)
#pragma unroll
    for (int i = 0; i < 2; ++i) {
      const int q = t + i * 256;
      const int row = q >> 3, c8 = q & 7;
      const float* Af =
          X + (long)g * NN * FF + (long)(m0 + row) * FF + kb + c8 * 8;
      float4 f0 = *(const float4*)Af;
      float4 f1 = *(const float4*)(Af + 4);
      ushort8 v;
      v[0] = f2bf(f0.x); v[1] = f2bf(f0.y); v[2] = f2bf(f0.z); v[3] = f2bf(f0.w);
      v[4] = f2bf(f1.x); v[5] = f2bf(f1.y); v[6] = f2bf(f1.z); v[7] = f2bf(f1.w);
      *(ushort8*)&As[row * 72 + c8 * 8] = v;
    }
    // B: w_in fp32 [k][256] -> Bs[n][k] transpose, all 256 cols
    {
      const int row = t >> 2;
      const int c0 = (t & 3) * 16;
#pragma unroll
      for (int nb = 0; nb < 4; ++nb) {
#pragma unroll
        for (int jj = 0; jj < 4; ++jj) {
          float4 f = *(const float4*)&w_in[(long)(kb + row) * HH + nb * 64 +
                                           c0 + jj * 4];
          Bs[(nb * 64 + c0 + jj * 4 + 0) * 72 + row] = f2bf(f.x);
          Bs[(nb * 64 + c0 + jj * 4 + 1) * 72 + row] = f2bf(f.y);
          Bs[(nb * 64 + c0 + jj * 4 + 2) * 72 + row] = f2bf(f.z);
          Bs[(nb * 64 + c0 + jj * 4 + 3) * 72 + row] = f2bf(f.w);
        }
      }
    }
    __syncthreads();
#pragma unroll
    for (int kk = 0; kk < 64; kk += 32) {
      const int ko = kk + quad * 8;
      short8 a = *(const short8*)&As[(w * 16 + l16) * 72 + ko];
#pragma unroll
      for (int j = 0; j < 16; ++j) {
        short8 b = *(const short8*)&Bs[(j * 16 + l16) * 72 + ko];
        acc[j] = __builtin_amdgcn_mfma_f32_16x16x32_bf16(a, b, acc[j], 0, 0, 0);
      }
    }
  }

  // epilogue 1: x0 = relu(acc + b) -> h0bf + Xs
#pragma unroll
  for (int j = 0; j < 16; ++j) {
    const int n = j * 16 + l16;
    const float bv = b_in[n];
#pragma unroll
    for (int r = 0; r < 4; ++r) {
      const int mr = w * 16 + quad * 4 + r;
      const unsigned short pv = f2bf(fmaxf(acc[j][r] + bv, 0.f));
      h0bf[(long)g * NN * HH + (long)(m0 + mr) * HH + n] = pv;
      Xs[mr * 264 + n] = pv;
    }
  }

  // phase 2: y0 = x0 @ W0, K=256 in 4 steps of 64
  floatx4 acc2[16];
#pragma unroll
  for (int j = 0; j < 16; ++j) acc2[j] = (floatx4){0.f, 0.f, 0.f, 0.f};

  for (int tt = 0; tt < 4; ++tt) {
    const int kb = tt * 64;
    __syncthreads();  // all prior Bs reads complete (cross-wave)
    {
      const int row = t >> 2;
      const int c0 = (t & 3) * 16;
#pragma unroll
      for (int nb = 0; nb < 4; ++nb) {
#pragma unroll
        for (int jj = 0; jj < 4; ++jj) {
          float4 f = *(const float4*)&gcn_w0[(long)(kb + row) * HH + nb * 64 +
                                             c0 + jj * 4];
          Bs[(nb * 64 + c0 + jj * 4 + 0) * 72 + row] = f2bf(f.x);
          Bs[(nb * 64 + c0 + jj * 4 + 1) * 72 + row] = f2bf(f.y);
          Bs[(nb * 64 + c0 + jj * 4 + 2) * 72 + row] = f2bf(f.z);
          Bs[(nb * 64 + c0 + jj * 4 + 3) * 72 + row] = f2bf(f.w);
        }
      }
    }
    __syncthreads();
#pragma unroll
    for (int kk = 0; kk < 64; kk += 32) {
      const int ko = kk + quad * 8;
      short8 a = *(const short8*)&Xs[(w * 16 + l16) * 264 + kb + ko];
#pragma unroll
      for (int j = 0; j < 16; ++j) {
        short8 b = *(const short8*)&Bs[(j * 16 + l16) * 72 + ko];
        acc2[j] = __builtin_amdgcn_mfma_f32_16x16x32_bf16(a, b, acc2[j], 0, 0, 0);
      }
    }
  }

  // epilogue 2: yT[g][n][m] transposed store (g1 epilogue pattern)
#pragma unroll
  for (int j = 0; j < 16; ++j) {
    const int n = j * 16 + l16;
    ushort4v pv;
#pragma unroll
    for (int r = 0; r < 4; ++r) pv[r] = f2bf(acc2[j][r]);
    *(ushort4v*)&yT[(long)g * HH * NN + (long)n * NN + m0 + w * 16 + quad * 4] =
        pv;
  }
}

// ---- misc jobs (verified) ----
__device__ void mask_job(int b, const void* __restrict__ cp_mask,
                         float* __restrict__ fmask, float* __restrict__ denom,
                         int t) {
  const unsigned char* bytes = (const unsigned char*)cp_mask;
  __shared__ int fmt;
  __shared__ float red[256];
  if (t == 0) {
    int any = 0;
    for (int i = 0; i < 256; ++i)
      if ((i & 3) && bytes[i]) any = 1;
    fmt = any ? 0 : 1;
  }
  __syncthreads();
  float cnt = 0.f;
  for (int n = t; n < NN; n += 256) {
    float v;
    if (fmt)
      v = ((const int*)cp_mask)[b * NN + n] ? 1.f : 0.f;
    else
      v = bytes[b * NN + n] ? 1.f : 0.f;
    fmask[b * NN + n] = v;
    cnt += v;
  }
  red[t] = cnt;
  __syncthreads();
  for (int s = 128; s > 0; s >>= 1) {
    if (t < s) red[t] += red[t + s];
    __syncthreads();
  }
  if (t == 0) denom[b] = fmaxf(red[0], 1.f);
}

__device__ void gw_job(int j, const float* __restrict__ gcn_w,
                       unsigned short* __restrict__ gwT, int t) {
  const int l = j >> 4, r0 = (j & 15) * 16;
  const float* src = gcn_w + (long)l * HH * HH;
  unsigned short* dst = gwT + (long)l * HH * HH;
  unsigned short vv[16];
#pragma unroll
  for (int rr = 0; rr < 16; ++rr) vv[rr] = f2bf(src[(long)(r0 + rr) * HH + t]);
  *(ushort8*)&dst[(long)t * HH + r0] = *(ushort8*)&vv[0];
  *(ushort8*)&dst[(long)t * HH + r0 + 8] = *(ushort8*)&vv[8];
}

// ---------------------------------------------------------------------------
// pre64_kernel: [0,1024) A fp32->bf16; [1024,1088) in64 (x0 + y0);
// [1088,1136) gwT for layers 1..3; [1136,1168) mask + zero-out.
// ---------------------------------------------------------------------------
__global__ __launch_bounds__(256) void pre64_kernel(
    const float* __restrict__ batch_as, unsigned short* __restrict__ Abf,
    const float* __restrict__ batch_xs, const float* __restrict__ w_in,
    const float* __restrict__ b_in, const float* __restrict__ gcn_w,
    unsigned short* __restrict__ h0bf, unsigned short* __restrict__ yT0,
    unsigned short* __restrict__ gwT, const void* __restrict__ cp_mask,
    float* __restrict__ fmask, float* __restrict__ denom,
    float* __restrict__ out) {
  __shared__ __align__(16) unsigned short As[64 * 72];
  __shared__ __align__(16) unsigned short Bs[256 * 72];
  __shared__ __align__(16) unsigned short Xs[64 * 264];
  const int b = blockIdx.x, t = threadIdx.x;
  if (b < 1024) {
    const long idx = ((long)b * 256 + t) * 16;
#pragma unroll
    for (int h = 0; h < 2; ++h) {
      float4 f0 = *(const float4*)&batch_as[idx + h * 8];
      float4 f1 = *(const float4*)&batch_as[idx + h * 8 + 4];
      ushort8 v;
      v[0] = f2bf(f0.x); v[1] = f2bf(f0.y); v[2] = f2bf(f0.z); v[3] = f2bf(f0.w);
      v[4] = f2bf(f1.x); v[5] = f2bf(f1.y); v[6] = f2bf(f1.z); v[7] = f2bf(f1.w);
      *(ushort8*)&Abf[idx + h * 8] = v;
    }
  } else if (b < 1088) {
    in64_tile(b - 1024, batch_xs, w_in, b_in, gcn_w, h0bf, yT0, As, Bs, Xs, t);
  } else if (b < 1136) {
    gw_job(16 + (b - 1088), gcn_w, gwT, t);  // layers 1..3 only
  } else {
    const int bb = b - 1136;
    out[bb * HH + t] = 0.f;
    mask_job(bb, cp_mask, fmask, denom, t);
  }
}

// ---------------------------------------------------------------------------
// g1: yT = (x @ W_l)^T bf16 [g][n][m]. 64x64 tile, register prefetch.
// [verified]
// ---------------------------------------------------------------------------
__global__ __launch_bounds__(256) void g1_kernel(
    const unsigned short* __restrict__ xbf,
    const unsigned short* __restrict__ WT,
    unsigned short* __restrict__ yT) {
  __shared__ __align__(16) unsigned short As[64 * 72];
  __shared__ __align__(16) unsigned short Bs[64 * 72];
  const int n0 = blockIdx.x * 64;
  const int m0 = blockIdx.y * 64;
  const int g = blockIdx.z;
  const int t = threadIdx.x;
  const int lane = t & 63, w = t >> 6;
  const int wm = w & 1, wn = w >> 1;
  const int l16 = lane & 15, quad = lane >> 4;

  const unsigned short* Ab = xbf + (long)g * NN * HH;

  ushort8 pa[2], pb[2];
  auto load_tile = [&](int tt) {
    const int kb = tt * 64;
#pragma unroll
    for (int i = 0; i < 2; ++i) {
      const int q = t + i * 256;
      const int row = q >> 3, c8 = q & 7;
      pa[i] = *(const ushort8*)&Ab[(long)(m0 + row) * HH + kb + c8 * 8];
      pb[i] = *(const ushort8*)&WT[(long)(n0 + row) * HH + kb + c8 * 8];
    }
  };
  auto store_tile = [&]() {
#pragma unroll
    for (int i = 0; i < 2; ++i) {
      const int q = t + i * 256;
      const int row = q >> 3, c8 = q & 7;
      *(ushort8*)&As[row * 72 + c8 * 8] = pa[i];
      *(ushort8*)&Bs[row * 72 + c8 * 8] = pb[i];
    }
  };

  floatx4 acc[2][2];
#pragma unroll
  for (int i = 0; i < 2; ++i)
#pragma unroll
    for (int j = 0; j < 2; ++j) acc[i][j] = (floatx4){0.f, 0.f, 0.f, 0.f};

  load_tile(0);
  for (int tt = 0; tt < 4; ++tt) {
    __syncthreads();
    store_tile();
    __syncthreads();
    if (tt + 1 < 4) load_tile(tt + 1);
#pragma unroll
    for (int kk = 0; kk < 64; kk += 32) {
      const int ko = kk + quad * 8;
      short8 a0 = *(const short8*)&As[(wm * 32 + l16) * 72 + ko];
      short8 a1 = *(const short8*)&As[(wm * 32 + 16 + l16) * 72 + ko];
      short8 b0 = *(const short8*)&Bs[(wn * 32 + l16) * 72 + ko];
      short8 b1 = *(const short8*)&Bs[(wn * 32 + 16 + l16) * 72 + ko];
      acc[0][0] = __builtin_amdgcn_mfma_f32_16x16x32_bf16(a0, b0, acc[0][0], 0, 0, 0);
      acc[0][1] = __builtin_amdgcn_mfma_f32_16x16x32_bf16(a0, b1, acc[0][1], 0, 0, 0);
      acc[1][0] = __builtin_amdgcn_mfma_f32_16x16x32_bf16(a1, b0, acc[1][0], 0, 0, 0);
      acc[1][1] = __builtin_amdgcn_mfma_f32_16x16x32_bf16(a1, b1, acc[1][1], 0, 0, 0);
    }
  }

#pragma unroll
  for (int i = 0; i < 2; ++i) {
#pragma unroll
    for (int j = 0; j < 2; ++j) {
      const int n = n0 + wn * 32 + j * 16 + l16;
      const int mB = m0 + wm * 32 + i * 16 + quad * 4;
      ushort4v pv;
#pragma unroll
      for (int r = 0; r < 4; ++r) pv[r] = f2bf(acc[i][j][r]);
      *(ushort4v*)&yT[(long)g * HH * NN + (long)n * NN + mB] = pv;
    }
  }
}

// ---------------------------------------------------------------------------
// g2<ACT>: T = A @ y (32x64 tile, BK=128, register prefetch). [verified]
// ACT=1: xbf = relu(T + bias); ACT=0: tanh + residual + masked mean.
// ---------------------------------------------------------------------------
template <int ACT>
__global__ __launch_bounds__(256) void g2_kernel(
    const unsigned short* __restrict__ Abf,
    const unsigned short* __restrict__ yT, const float* __restrict__ bias,
    const unsigned short* __restrict__ h0bf, unsigned short* __restrict__ xbf,
    const float* __restrict__ fmask, const float* __restrict__ denom,
    const int* __restrict__ gidx, float* __restrict__ out) {
  __shared__ __align__(16) unsigned short As[32 * 136];
  __shared__ __align__(16) unsigned short Bs[64 * 136];
  const int n0 = blockIdx.x * 64;
  const int m0 = blockIdx.y * 32;
  const int g = blockIdx.z;
  const int t = threadIdx.x;
  const int lane = t & 63, w = t >> 6;
  const int wm = w & 1, wn = w >> 1;
  const int l16 = lane & 15, quad = lane >> 4;

  const unsigned short* Ag = Abf + (long)g * NN * NN + (long)m0 * NN;
  const unsigned short* Bg = yT + (long)g * HH * NN + (long)n0 * NN;

  ushort8 pa[2], pb[4];
  auto load_tile = [&](int tt) {
    const int kb = tt * 128;
#pragma unroll
    for (int i = 0; i < 2; ++i) {
      const int q = t + i * 256;
      const int row = q >> 4, c8 = q & 15;
      pa[i] = *(const ushort8*)&Ag[(long)row * NN + kb + c8 * 8];
    }
#pragma unroll
    for (int i = 0; i < 4; ++i) {
      const int q = t + i * 256;
      const int row = q >> 4, c8 = q & 15;
      pb[i] = *(const ushort8*)&Bg[(long)row * NN + kb + c8 * 8];
    }
  };
  auto store_tile = [&]() {
#pragma unroll
    for (int i = 0; i < 2; ++i) {
      const int q = t + i * 256;
      const int row = q >> 4, c8 = q & 15;
      *(ushort8*)&As[row * 136 + c8 * 8] = pa[i];
    }
#pragma unroll
    for (int i = 0; i < 4; ++i) {
      const int q = t + i * 256;
      const int row = q >> 4, c8 = q & 15;
      *(ushort8*)&Bs[row * 136 + c8 * 8] = pb[i];
    }
  };

  floatx4 acc[2];
  acc[0] = (floatx4){0.f, 0.f, 0.f, 0.f};
  acc[1] = (floatx4){0.f, 0.f, 0.f, 0.f};

  load_tile(0);
  for (int tt = 0; tt < 8; ++tt) {
    __syncthreads();
    store_tile();
    __syncthreads();
    if (tt + 1 < 8) load_tile(tt + 1);
#pragma unroll
    for (int kk = 0; kk < 128; kk += 32) {
      const int ko = kk + quad * 8;
      short8 a = *(const short8*)&As[(wm * 16 + l16) * 136 + ko];
      short8 b0 = *(const short8*)&Bs[(wn * 32 + l16) * 136 + ko];
      short8 b1 = *(const short8*)&Bs[(wn * 32 + 16 + l16) * 136 + ko];
      acc[0] = __builtin_amdgcn_mfma_f32_16x16x32_bf16(a, b0, acc[0], 0, 0, 0);
      acc[1] = __builtin_amdgcn_mfma_f32_16x16x32_bf16(a, b1, acc[1], 0, 0, 0);
    }
  }

  if (ACT == 1) {
#pragma unroll
    for (int j = 0; j < 2; ++j) {
      const int n = n0 + wn * 32 + j * 16 + l16;
      const int mB = m0 + wm * 16 + quad * 4;
      const float bv = bias[n];
#pragma unroll
      for (int r = 0; r < 4; ++r)
        xbf[(long)g * NN * HH + (long)(mB + r) * HH + n] =
            f2bf(fmaxf(acc[j][r] + bv, 0.f));
    }
  } else {
    const int mB0 = m0 + wm * 16 + quad * 4;
    float zv[2][4];
#pragma unroll
    for (int j = 0; j < 2; ++j) {
      const int n = n0 + wn * 32 + j * 16 + l16;
      const float bv = bias[n];
#pragma unroll
      for (int r = 0; r < 4; ++r) {
        const long idx = (long)g * NN * HH + (long)(mB0 + r) * HH + n;
        zv[j][r] = tanhf(acc[j][r] + bv) + bf2f(h0bf[idx]);
      }
    }
    for (int b = 0; b < BB; ++b) {
      if (gidx[b] != g) continue;  // block-uniform branch
      const float invd = 1.f / denom[b];
      float m4[4];
#pragma unroll
      for (int r = 0; r < 4; ++r) m4[r] = fmask[b * NN + mB0 + r];
#pragma unroll
      for (int j = 0; j < 2; ++j) {
        float p = m4[0] * zv[j][0] + m4[1] * zv[j][1] + m4[2] * zv[j][2] +
                  m4[3] * zv[j][3];
        p += __shfl_xor(p, 16);
        p += __shfl_xor(p, 32);
        if (quad == 0) {
          const int n = n0 + wn * 32 + j * 16 + l16;
          atomicAdd(&out[b * HH + n], p * invd);
        }
      }
    }
  }
}

extern "C" void kernel_launch(void* const* d_in, const int* in_sizes, int n_in,
                              void* d_out, int out_size, void* d_ws,
                              size_t ws_size, hipStream_t stream) {
  (void)in_sizes; (void)n_in; (void)out_size; (void)ws_size;
  const float* batch_xs = (const float*)d_in[0];
  const float* batch_as = (const float*)d_in[1];
  const float* w_in = (const float*)d_in[2];
  const float* b_in = (const float*)d_in[3];
  const float* gcn_w = (const float*)d_in[4];
  const float* gcn_b = (const float*)d_in[5];
  const int* graph_idx = (const int*)d_in[6];
  const void* cp_mask = d_in[7];
  float* out = (float*)d_out;

  char* p = (char*)d_ws;
  unsigned short* Abf = (unsigned short*)p;  p += (long)G * NN * NN * 2;
  unsigned short* gwT = (unsigned short*)p;  p += (long)LL * HH * HH * 2;
  unsigned short* xbf = (unsigned short*)p;  p += (long)G * NN * HH * 2;
  unsigned short* h0bf = (unsigned short*)p; p += (long)G * NN * HH * 2;
  unsigned short* yTa = (unsigned short*)p;  p += (long)G * HH * NN * 2;
  unsigned short* yTb = (unsigned short*)p;  p += (long)G * HH * NN * 2;
  float* fmask = (float*)p;                  p += (long)BB * NN * 4;
  float* denom = (float*)p;                  p += BB * 4;

  // pre: A->bf16, x0 (-> h0bf) AND y0 (-> yTa), gwT(1..3), mask, zero-out.
  pre64_kernel<<<1168, 256, 0, stream>>>(batch_as, Abf, batch_xs, w_in, b_in,
                                         gcn_w, h0bf, yTa, gwT, cp_mask,
                                         fmask, denom, out);

  // x1 = relu(A@y0 + b0)
  g2_kernel<1><<<dim3(4, 32, G), 256, 0, stream>>>(
      Abf, yTa, gcn_b + 0 * HH, nullptr, xbf, nullptr, nullptr, nullptr,
      nullptr);
  // y1 = x1 @ W1
  g1_kernel<<<dim3(4, 16, G), 256, 0, stream>>>(xbf, gwT + (long)1 * HH * HH,
                                                yTb);
  // x2 = relu(A@y1 + b1)
  g2_kernel<1><<<dim3(4, 32, G), 256, 0, stream>>>(
      Abf, yTb, gcn_b + 1 * HH, nullptr, xbf, nullptr, nullptr, nullptr,
      nullptr);
  // y2 = x2 @ W2
  g1_kernel<<<dim3(4, 16, G), 256, 0, stream>>>(xbf, gwT + (long)2 * HH * HH,
                                                yTa);
  // x3 = relu(A@y2 + b2)
  g2_kernel<1><<<dim3(4, 32, G), 256, 0, stream>>>(
      Abf, yTa, gcn_b + 2 * HH, nullptr, xbf, nullptr, nullptr, nullptr,
      nullptr);
  // y3 = x3 @ W3
  g1_kernel<<<dim3(4, 16, G), 256, 0, stream>>>(xbf, gwT + (long)3 * HH * HH,
                                                yTb);
  // final: tanh(A@y3 + b3) + h0, masked mean
  g2_kernel<0><<<dim3(4, 32, G), 256, 0, stream>>>(
      Abf, yTb, gcn_b + (long)3 * HH, h0bf, nullptr, fmask, denom, graph_idx,
      out);
}